// Round 8
// baseline (253.528 us; speedup 1.0000x reference)
//
#include <hip/hip_runtime.h>
#include <hip/hip_bf16.h>

#define BB 16
#define LL 4096
#define CC 512
#define NG 128   // B*G
#define IC1 68
#define OC1 64
#define OC2 32

typedef short short8 __attribute__((ext_vector_type(8)));
typedef float f32x4 __attribute__((ext_vector_type(4)));

__device__ inline ushort f2b(float f) {
    __hip_bfloat16 h = __float2bfloat16(f);
    return *reinterpret_cast<ushort*>(&h);
}
__device__ inline float b2f(ushort u) {
    __hip_bfloat16 h;
    *reinterpret_cast<ushort*>(&h) = u;
    return __bfloat162float(h);
}
__device__ inline float fast_tanh(float y) {
    float e = __expf(2.0f * y);
    return 1.0f - 2.0f / (e + 1.0f);
}
__device__ inline float fast_gelu(float x) {
    float y = x * (0.7978845608f + 0.0356774081f * x * x);
    return 0.5f * x * (1.0f + fast_tanh(y));
}
__device__ inline short8 pack8(float4 a, float4 b) {
    short8 r;
    uint* u = (uint*)&r;
    u[0] = (uint)f2b(a.x) | ((uint)f2b(a.y) << 16);
    u[1] = (uint)f2b(a.z) | ((uint)f2b(a.w) << 16);
    u[2] = (uint)f2b(b.x) | ((uint)f2b(b.y) << 16);
    u[3] = (uint)f2b(b.z) | ((uint)f2b(b.w) << 16);
    return r;
}
__device__ inline float4 add4(float4 a, float4 b) {
    return make_float4(a.x + b.x, a.y + b.y, a.z + b.z, a.w + b.w);
}

// ---------------- prep: bf16 weights (padded), corr ----------------
__global__ __launch_bounds__(256) void k_prep(const float* __restrict__ x,
    const float* __restrict__ w1, const float* __restrict__ w2,
    const float* __restrict__ gate,
    ushort* __restrict__ w1b, ushort* __restrict__ w2b, float* __restrict__ corr)
{
    int idx = blockIdx.x * 256 + threadIdx.x;
    if (idx < 18432) {                       // w1b[k][oc][icp<96]
        int k = idx / 6144; int r = idx - k * 6144;
        int oc = r / 96;    int icp = r - oc * 96;
        float v = (icp < IC1) ? w1[(oc * IC1 + icp) * 3 + k] : 0.0f;
        w1b[idx] = f2b(v);
    } else if (idx < 24576) {                // w2b[k][oc][ic<64]
        int j = idx - 18432;
        int k = j / 2048; int r = j - k * 2048;
        int oc = r / 64;  int ic = r - oc * 64;
        w2b[j] = f2b(w2[(oc * OC1 + ic) * 3 + k]);
    } else if (idx < 32768) {                // corr[b*512+ch]
        int i3 = idx - 24576;
        int b = i3 >> 9; int ch = i3 & 511;
        float tg = tanhf(gate[0]);
        corr[i3] = tg * 0.5f *
            (x[((size_t)(b * LL + 2047)) * CC + ch] +
             x[((size_t)(b * LL + 2048)) * CC + ch]);
    }
}

// ---------------- A: conv1 MFMA straight from global; no LDS, no barriers --
// wave owns 16 l-positions; lane (m = l-off, h = 8-ch group);
// fragments loaded directly: B[l=m][ic = c*32+h*8+j]; 36 MFMA -> all 64 oc.
// k=1 registers recycled into out = x+corr (fp32) and xbf (bf16) writes.
template<bool FULL>
__device__ __forceinline__ void ka_wave(
    const float* __restrict__ x, const float* __restrict__ xe,
    const float* __restrict__ b1, const ushort* __restrict__ w1b,
    const float* __restrict__ corr, float* __restrict__ part,
    float* __restrict__ out, ushort* __restrict__ xbf, int n, int l0)
{
    const int lane = threadIdx.x & 63;
    const int m = lane & 15, h = lane >> 4;
    const int b = n >> 3, g = n & 7, be = n & 15;

    f32x4 acc[4] = {};
    float4 k1lo[2], k1hi[2];
    short8 k1f[2];

#pragma unroll
    for (int k = 0; k < 3; ++k) {
        const int row = l0 + m + k - 1;
        const bool ok = FULL || ((unsigned)row < (unsigned)LL);
        const float* xp = x + ((size_t)b * LL + row) * CC + g * 64 + h * 8;
#pragma unroll
        for (int c = 0; c < 2; ++c) {
            float4 lo = make_float4(0.f, 0.f, 0.f, 0.f);
            float4 hi = make_float4(0.f, 0.f, 0.f, 0.f);
            if (ok) {
                lo = *(const float4*)(xp + c * 32);
                hi = *(const float4*)(xp + c * 32 + 4);
            }
            short8 fb = pack8(lo, hi);
            if (k == 1) { k1lo[c] = lo; k1hi[c] = hi; k1f[c] = fb; }
#pragma unroll
            for (int mt = 0; mt < 4; ++mt) {
                short8 fa = *(const short8*)&w1b[
                    (size_t)(k * 64 + mt * 16 + m) * 96 + c * 32 + h * 8];
                acc[mt] = __builtin_amdgcn_mfma_f32_16x16x32_bf16(fa, fb, acc[mt], 0, 0, 0);
            }
        }
        // c = 2: xe channels 64-67 (+zero pad); only h==0 lanes carry data
        float4 xv = make_float4(0.f, 0.f, 0.f, 0.f);
        if (h == 0 && ok) xv = *(const float4*)(xe + ((size_t)be * LL + row) * 4);
        short8 fb2 = pack8(xv, make_float4(0.f, 0.f, 0.f, 0.f));
#pragma unroll
        for (int mt = 0; mt < 4; ++mt) {
            short8 fa = *(const short8*)&w1b[
                (size_t)(k * 64 + mt * 16 + m) * 96 + 64 + h * 8];
            acc[mt] = __builtin_amdgcn_mfma_f32_16x16x32_bf16(fa, fb2, acc[mt], 0, 0, 0);
        }
    }

    // fused out = x + corr, xbf = bf16(x), from k=1 registers (row always valid)
    {
        const int l = l0 + m;
        const int cb = (b << 9) + g * 64 + h * 8;
        float4 ca0 = *(const float4*)&corr[cb];
        float4 ca1 = *(const float4*)&corr[cb + 4];
        float4 cb0 = *(const float4*)&corr[cb + 32];
        float4 cb1 = *(const float4*)&corr[cb + 36];
        float* op = out + ((size_t)b * LL + l) * CC + g * 64 + h * 8;
        *(float4*)(op)      = add4(k1lo[0], ca0);
        *(float4*)(op + 4)  = add4(k1hi[0], ca1);
        *(float4*)(op + 32) = add4(k1lo[1], cb0);
        *(float4*)(op + 36) = add4(k1hi[1], cb1);
        ushort* bp = xbf + ((size_t)n * LL + l) * 64 + h * 8;
        *(short8*)(bp)      = k1f[0];
        *(short8*)(bp + 32) = k1f[1];
    }

    // group sums: GN group == mt; butterfly over the wave
    const int seg = l0 >> 4;
#pragma unroll
    for (int mt = 0; mt < 4; ++mt) {
        float4 bv = *(const float4*)&b1[mt * 16 + h * 4];
        float v0 = acc[mt][0] + bv.x, v1 = acc[mt][1] + bv.y;
        float v2 = acc[mt][2] + bv.z, v3 = acc[mt][3] + bv.w;
        float a = (v0 + v1) + (v2 + v3);
        float q = v0 * v0 + v1 * v1 + v2 * v2 + v3 * v3;
#pragma unroll
        for (int off = 32; off > 0; off >>= 1) {
            a += __shfl_xor(a, off, 64);
            q += __shfl_xor(q, off, 64);
        }
        if (lane == 0) {
            float* pp = part + (((size_t)n * 4 + mt) * 256 + seg) * 2;
            pp[0] = a; pp[1] = q;
        }
    }
}

__global__ __launch_bounds__(256, 4) void ka_conv(const float* __restrict__ x,
    const float* __restrict__ xe, const float* __restrict__ b1,
    const ushort* __restrict__ w1b, const float* __restrict__ corr,
    float* __restrict__ part, float* __restrict__ out, ushort* __restrict__ xbf)
{
    const int n = blockIdx.y, blk = blockIdx.x;
    const int l0 = (blk * 4 + (threadIdx.x >> 6)) * 16;
    if (blk >= 1 && blk <= 62)
        ka_wave<true >(x, xe, b1, w1b, corr, part, out, xbf, n, l0);
    else
        ka_wave<false>(x, xe, b1, w1b, corr, part, out, xbf, n, l0);
}

// ---------------- B: fused second pass (pure compute, linear-copy staging) -
// offs l in [l0, l0+60); h2 j <-> l=l0-1+j; h p <-> l=l0-2+p; rows li <-> l=l0-3+li
// pin: [66] rows x 8 chunks(16B), chunk stored at (ch ^ (row&7))  [xbf copy]
// xeb: [66] rows x 4 chunks(16B), chunk stored at (ch ^ (row&3))  [xe 32-pad]
#define BT 60
#define XR 66
#define P2S  72
#define H2S  66
template<bool FULL>
__device__ __forceinline__ void kb_body(ushort* smem, float* sstats,
    const float* __restrict__ xe, const ushort* __restrict__ xbf,
    const float* __restrict__ part, const float* __restrict__ b1,
    const ushort* __restrict__ w1b, const float* __restrict__ gn_g,
    const float* __restrict__ gn_b, const float* __restrict__ b2,
    const ushort* __restrict__ w2b, const float* __restrict__ w3,
    float* __restrict__ offs, int n, int lt)
{
    ushort* pin = smem;              // 66*64 = 4224 ush (phases 1-2)
    ushort* xeb = smem + 4224;       // 66*32 = 2112 ush (phases 1-2)
    ushort* p2  = smem;              // 66*72 = 4752 ush (phases 3-4, aliases)
    ushort* h2b = smem + 4752;       // 32*66 = 2112 ush (phases 4-5, aliases xeb tail)
    const int be = n & 15;
    const int l0 = lt * BT;
    const int t = threadIdx.x;
    const int lane = t & 63;
    const int w = t >> 6;            // 0/1

    // stats: wave w reduces GN groups 2w, 2w+1 (part 2KB/group, L2-hot)
#pragma unroll
    for (int gg = 0; gg < 2; ++gg) {
        int gidx = w * 2 + gg;
        const float2* pp = (const float2*)&part[(((size_t)n * 4 + gidx) * 256) * 2];
        float s1 = 0.f, s2 = 0.f;
#pragma unroll
        for (int j = 0; j < 4; ++j) {
            float2 p = pp[lane + j * 64];
            s1 += p.x; s2 += p.y;
        }
#pragma unroll
        for (int off = 32; off > 0; off >>= 1) {
            s1 += __shfl_down(s1, off, 64);
            s2 += __shfl_down(s2, off, 64);
        }
        if (lane == 0) {
            float mean = s1 * (1.0f / 65536.0f);
            float var  = s2 * (1.0f / 65536.0f) - mean * mean;
            sstats[gidx * 2 + 0] = mean;
            sstats[gidx * 2 + 1] = 1.0f / sqrtf(var + 1e-5f);
        }
    }

    // phase 1a: linear copy xbf -> pin (swizzled chunk placement, no cvt)
    {
        const uint4* xs = (const uint4*)(xbf + ((size_t)n * LL + (l0 - 3)) * 64);
#pragma unroll
        for (int i = 0; i < 5; ++i) {
            int s = t + i * 128;
            if (s < XR * 8) {
                int row = s >> 3, ch = s & 7;
                uint4 v;
                if (FULL) {
                    v = xs[s];
                } else {
                    int l = l0 - 3 + row;
                    v = make_uint4(0u, 0u, 0u, 0u);
                    if (l >= 0 && l < LL) v = xs[s];
                }
                ((uint4*)pin)[(row << 3) | (ch ^ (row & 7))] = v;
            }
        }
    }
    // phase 1b: xe (tiny, L2-hot) -> xeb rows [4 real + 28 zero]
    if (t < XR) {
        int l = l0 - 3 + t;
        float4 v = make_float4(0.f, 0.f, 0.f, 0.f);
        if (FULL || (l >= 0 && l < LL))
            v = *(const float4*)&xe[(size_t)(be * LL + l) * 4];
        uint lo = (uint)f2b(v.x) | ((uint)f2b(v.y) << 16);
        uint hi = (uint)f2b(v.z) | ((uint)f2b(v.w) << 16);
        int sw = t & 3;
        uint4 z = make_uint4(0u, 0u, 0u, 0u);
        ((uint4*)xeb)[(t << 2) | (0 ^ sw)] = make_uint4(lo, hi, 0u, 0u);
        ((uint4*)xeb)[(t << 2) | (1 ^ sw)] = z;
        ((uint4*)xeb)[(t << 2) | (2 ^ sw)] = z;
        ((uint4*)xeb)[(t << 2) | (3 ^ sw)] = z;
    }
    __syncthreads();

    // phase 2: conv1 MFMA (recompute), acc in registers
    const int m = lane & 15, h = lane >> 4;

    short8 fa[2][9];
#pragma unroll
    for (int mi = 0; mi < 2; ++mi)
#pragma unroll
        for (int k = 0; k < 3; ++k)
#pragma unroll
            for (int c = 0; c < 3; ++c)
                fa[mi][k * 3 + c] = *(const short8*)&w1b[
                    (size_t)(k * 64 + w * 32 + mi * 16 + m) * 96 + c * 32 + h * 8];

    f32x4 acc[2][4] = {};
#pragma unroll
    for (int tt = 0; tt < 4; ++tt) {
        const int p = tt * 16 + m;       // h pos; x row = p + k
#pragma unroll
        for (int k = 0; k < 3; ++k) {
            const int row = p + k;
#pragma unroll
            for (int c = 0; c < 3; ++c) {
                short8 fb;
                if (c < 2)
                    fb = *(const short8*)&pin[(size_t)(((row << 3) | ((c * 4 + h) ^ (row & 7))) << 3)];
                else
                    fb = *(const short8*)&xeb[(size_t)(((row << 2) | (h ^ (row & 3))) << 3)];
                acc[0][tt] = __builtin_amdgcn_mfma_f32_16x16x32_bf16(fa[0][k * 3 + c], fb, acc[0][tt], 0, 0, 0);
                acc[1][tt] = __builtin_amdgcn_mfma_f32_16x16x32_bf16(fa[1][k * 3 + c], fb, acc[1][tt], 0, 0, 0);
            }
        }
    }
    __syncthreads();   // pin/xeb dead; p2 may overwrite

    // phase 3: bias+GN+GELU -> p2[p][oc] (bf16), p = 0..63
#pragma unroll
    for (int mi = 0; mi < 2; ++mi) {
        int gi = w * 2 + mi;
        float mean = sstats[gi * 2], istd = sstats[gi * 2 + 1];
        float A_[4], B_[4];
#pragma unroll
        for (int r = 0; r < 4; ++r) {
            int oc = w * 32 + mi * 16 + h * 4 + r;
            float ga = gn_g[oc];
            A_[r] = istd * ga;
            B_[r] = gn_b[oc] + (b1[oc] - mean) * A_[r];
        }
#pragma unroll
        for (int tt = 0; tt < 4; ++tt) {
            int p = tt * 16 + m;
            uint2 pk = make_uint2(0u, 0u);
            int l = l0 - 2 + p;
            if (FULL || (l >= 0 && l < LL)) {
                float v0 = fast_gelu(fmaf(acc[mi][tt][0], A_[0], B_[0]));
                float v1 = fast_gelu(fmaf(acc[mi][tt][1], A_[1], B_[1]));
                float v2 = fast_gelu(fmaf(acc[mi][tt][2], A_[2], B_[2]));
                float v3 = fast_gelu(fmaf(acc[mi][tt][3], A_[3], B_[3]));
                pk.x = (uint)f2b(v0) | ((uint)f2b(v1) << 16);
                pk.y = (uint)f2b(v2) | ((uint)f2b(v3) << 16);
            }
            *(uint2*)&p2[p * P2S + w * 32 + mi * 16 + h * 4] = pk;
        }
    }
    __syncthreads();

    // phase 4: conv2 MFMA + GELU -> h2b; wave w owns oc-tile w (16 oc)
    short8 fa2[6];
#pragma unroll
    for (int k = 0; k < 3; ++k)
#pragma unroll
        for (int c = 0; c < 2; ++c)
            fa2[k * 2 + c] = *(const short8*)&w2b[
                (size_t)(k * 32 + w * 16 + m) * 64 + c * 32 + h * 8];

    float bias2[4];
#pragma unroll
    for (int r = 0; r < 4; ++r)
        bias2[r] = b2[w * 16 + h * 4 + r];

    f32x4 acc2[4] = {};
#pragma unroll
    for (int u = 0; u < 4; ++u) {
        const int jb = u * 16 + m;      // h2 col j; rows>63 only feed unused j
#pragma unroll
        for (int k = 0; k < 3; ++k) {
#pragma unroll
            for (int c = 0; c < 2; ++c) {
                short8 fb = *(const short8*)&p2[(jb + k) * P2S + c * 32 + h * 8];
                acc2[u] = __builtin_amdgcn_mfma_f32_16x16x32_bf16(fa2[k * 2 + c], fb, acc2[u], 0, 0, 0);
            }
        }
    }
#pragma unroll
    for (int u = 0; u < 4; ++u) {
        int j = u * 16 + m;
        int lj = l0 - 1 + j;
#pragma unroll
        for (int r = 0; r < 4; ++r) {
            int oc = w * 16 + h * 4 + r;
            float v = 0.f;
            if (FULL || (lj >= 0 && lj < LL))
                v = fast_gelu(acc2[u][r] + bias2[r]);
            h2b[oc * H2S + j] = f2b(v);    // j=62..65 garbage-adjacent, never read
        }
    }
    __syncthreads();

    // phase 5: conv3 + tanh*10; (qq, half): 16 ic each, pair-reduce
    if (t < 2 * BT) {
        int qq = t >> 1, half = t & 1;
        int ic0 = half * 16;
        float a = 0.f;
#pragma unroll
        for (int ic = 0; ic < 16; ++ic) {
            int icc = ic0 + ic;
            float v0 = b2f(h2b[icc * H2S + qq]);
            float v1 = b2f(h2b[icc * H2S + qq + 1]);
            float v2 = b2f(h2b[icc * H2S + qq + 2]);
            a = fmaf(w3[icc * 3 + 0], v0, a);
            a = fmaf(w3[icc * 3 + 1], v1, a);
            a = fmaf(w3[icc * 3 + 2], v2, a);
        }
        a += __shfl_xor(a, 1, 64);
        if (half == 0) {
            int l = l0 + qq;
            if (FULL || l < LL)
                offs[(size_t)n * LL + l] = fast_tanh(a) * 10.0f;
        }
    }
}

__global__ __launch_bounds__(128, 4) void kb_fused(const float* __restrict__ xe,
    const ushort* __restrict__ xbf, const float* __restrict__ part,
    const float* __restrict__ b1, const ushort* __restrict__ w1b,
    const float* __restrict__ gn_g, const float* __restrict__ gn_b,
    const float* __restrict__ b2, const ushort* __restrict__ w2b,
    const float* __restrict__ w3, float* __restrict__ offs)
{
    __shared__ ushort smem[6864];   // 13728 B: (pin|xeb) aliased by (p2|h2b)
    __shared__ float sstats[8];
    const int n = blockIdx.y, lt = blockIdx.x;
    if (lt >= 1 && lt <= 67)
        kb_body<true >(smem, sstats, xe, xbf, part, b1, w1b, gn_g, gn_b, b2, w2b, w3, offs, n, lt);
    else
        kb_body<false>(smem, sstats, xe, xbf, part, b1, w1b, gn_g, gn_b, b2, w2b, w3, offs, n, lt);
}

extern "C" void kernel_launch(void* const* d_in, const int* in_sizes, int n_in,
                              void* d_out, int out_size, void* d_ws, size_t ws_size,
                              hipStream_t stream)
{
    const float* x    = (const float*)d_in[0];
    const float* xext = (const float*)d_in[1];
    const float* w1   = (const float*)d_in[2];
    const float* b1   = (const float*)d_in[3];
    const float* gng  = (const float*)d_in[4];
    const float* gnb  = (const float*)d_in[5];
    const float* w2   = (const float*)d_in[6];
    const float* b2   = (const float*)d_in[7];
    const float* w3   = (const float*)d_in[8];
    const float* gate = (const float*)d_in[9];

    float* out  = (float*)d_out;
    float* offs = out + (size_t)BB * LL * CC;        // 33,554,432

    char* ws = (char*)d_ws;
    float* part = (float*)(ws);                      // 1,048,576 B (128*4*256*2 f32)
    ushort* w1b = (ushort*)(ws + 1048576);           // 36,864 B
    ushort* w2b = (ushort*)(ws + 1085440);           // 12,288 B
    float* corr = (float*)(ws + 1097728);            // 32,768 B
    ushort* xbf = (ushort*)(ws + 1130496);           // 67,108,864 B

    k_prep<<<128, 256, 0, stream>>>(x, w1, w2, gate, w1b, w2b, corr);
    dim3 g1(64, NG);
    ka_conv<<<g1, 256, 0, stream>>>(x, xext, b1, w1b, corr, part, out, xbf);
    dim3 g3(69, NG);
    kb_fused<<<g3, 128, 0, stream>>>(xext, xbf, part, b1, w1b, gng, gnb, b2, w2b,
                                     w3, offs);
}

// Round 9
// 221.277 us; speedup vs baseline: 1.1458x; 1.1458x over previous
//
#include <hip/hip_runtime.h>
#include <hip/hip_bf16.h>

#define BB 16
#define LL 4096
#define CC 512
#define NG 128   // B*G
#define IC1 68
#define OC1 64
#define OC2 32

typedef short short8 __attribute__((ext_vector_type(8)));
typedef float f32x4 __attribute__((ext_vector_type(4)));

__device__ inline ushort f2b(float f) {
    __hip_bfloat16 h = __float2bfloat16(f);
    return *reinterpret_cast<ushort*>(&h);
}
__device__ inline float b2f(ushort u) {
    __hip_bfloat16 h;
    *reinterpret_cast<ushort*>(&h) = u;
    return __bfloat162float(h);
}
__device__ inline float fast_tanh(float y) {
    float e = __expf(2.0f * y);
    return 1.0f - 2.0f / (e + 1.0f);
}
__device__ inline float fast_gelu(float x) {
    float y = x * (0.7978845608f + 0.0356774081f * x * x);
    return 0.5f * x * (1.0f + fast_tanh(y));
}

// ---------------- prep: bf16 weights (padded), corr ----------------
__global__ __launch_bounds__(256) void k_prep(const float* __restrict__ x,
    const float* __restrict__ w1, const float* __restrict__ w2,
    const float* __restrict__ gate,
    ushort* __restrict__ w1b, ushort* __restrict__ w2b, float* __restrict__ corr)
{
    int idx = blockIdx.x * 256 + threadIdx.x;
    if (idx < 18432) {                       // w1b[k][oc][icp<96]
        int k = idx / 6144; int r = idx - k * 6144;
        int oc = r / 96;    int icp = r - oc * 96;
        float v = (icp < IC1) ? w1[(oc * IC1 + icp) * 3 + k] : 0.0f;
        w1b[idx] = f2b(v);
    } else if (idx < 24576) {                // w2b[k][oc][ic<64]
        int j = idx - 18432;
        int k = j / 2048; int r = j - k * 2048;
        int oc = r / 64;  int ic = r - oc * 64;
        w2b[j] = f2b(w2[(oc * OC1 + ic) * 3 + k]);
    } else if (idx < 32768) {                // corr[b*512+ch]
        int i3 = idx - 24576;
        int b = i3 >> 9; int ch = i3 & 511;
        float tg = tanhf(gate[0]);
        corr[i3] = tg * 0.5f *
            (x[((size_t)(b * LL + 2047)) * CC + ch] +
             x[((size_t)(b * LL + 2048)) * CC + ch]);
    }
}

// ---------------- A: persistent pipelined conv1 pass ----------------
// block = (chunk, n): 4 tiles x 128 l; per tile:
//   barrier; ds_write(t)+out/xbf stores(t); issue loads(t+1); barrier; MFMA(t)+sums
#define KA_ROWS 130
#define KA_STR  104   // ushorts per row (208 B)

struct KaRegs { float4 xq[9]; float4 xev; };

__device__ __forceinline__ void ka_load(KaRegs& r,
    const float* __restrict__ x, const float* __restrict__ xe,
    int b, int be, int g, int l0, int t)
{
    const int q = t & 15;
    const float* xb = x + ((size_t)b * LL + (l0 - 1)) * CC + g * 64 + q * 4;
#pragma unroll
    for (int i = 0; i < 9; ++i) {
        int pos = t + i * 256;
        if (pos < KA_ROWS * 16) {
            int li = pos >> 4;
            int l = l0 - 1 + li;
            r.xq[i] = make_float4(0.f, 0.f, 0.f, 0.f);
            if ((unsigned)l < (unsigned)LL)
                r.xq[i] = *(const float4*)(xb + (size_t)li * CC);
        }
    }
    if (t < KA_ROWS) {
        int l = l0 - 1 + t;
        r.xev = make_float4(0.f, 0.f, 0.f, 0.f);
        if ((unsigned)l < (unsigned)LL)
            r.xev = *(const float4*)(xe + ((size_t)be * LL + l) * 4);
    }
}

__device__ __forceinline__ void ka_write(ushort* pin, const KaRegs& r,
    const float4 corr0, float* __restrict__ out, ushort* __restrict__ xbf,
    int b, int g, int n, int l0, int t)
{
    const int q = t & 15;
#pragma unroll
    for (int i = 0; i < 9; ++i) {
        int pos = t + i * 256;
        if (pos < KA_ROWS * 16) {
            int li = pos >> 4;
            uint lo = (uint)f2b(r.xq[i].x) | ((uint)f2b(r.xq[i].y) << 16);
            uint hi = (uint)f2b(r.xq[i].z) | ((uint)f2b(r.xq[i].w) << 16);
            uint2 pk = make_uint2(lo, hi);
            *(uint2*)&pin[li * KA_STR + q * 4] = pk;
            if (li >= 1 && li <= 128) {
                int l = l0 - 1 + li;
                float4 o;
                o.x = r.xq[i].x + corr0.x; o.y = r.xq[i].y + corr0.y;
                o.z = r.xq[i].z + corr0.z; o.w = r.xq[i].w + corr0.w;
                *(float4*)(out + ((size_t)b * LL + l) * CC + g * 64 + q * 4) = o;
                *(uint2*)(xbf + ((size_t)n * LL + l) * 64 + q * 4) = pk;
            }
        }
    }
    if (t < KA_ROWS) {
        uint lo = (uint)f2b(r.xev.x) | ((uint)f2b(r.xev.y) << 16);
        uint hi = (uint)f2b(r.xev.z) | ((uint)f2b(r.xev.w) << 16);
        *(uint2*)&pin[t * KA_STR + 64] = make_uint2(lo, hi);
    }
}

__device__ __forceinline__ void ka_mfma(const ushort* pin,
    const float* __restrict__ b1, const ushort* __restrict__ w1b,
    float* __restrict__ part, int n, int lt, int w, int lane)
{
    const int m = lane & 15, h = lane >> 4;
    short8 fa[9];
#pragma unroll
    for (int k = 0; k < 3; ++k)
#pragma unroll
        for (int c = 0; c < 3; ++c)
            fa[k * 3 + c] = *(const short8*)&w1b[
                (size_t)(k * 64 + w * 16 + m) * 96 + c * 32 + h * 8];

    float4 bv = *(const float4*)&b1[w * 16 + h * 4];
    float s1 = 0.f, s2 = 0.f;
#pragma unroll
    for (int tt = 0; tt < 8; ++tt) {
        f32x4 acc = {};
        const int rowbase = tt * 16 + m;
#pragma unroll
        for (int k = 0; k < 3; ++k)
#pragma unroll
            for (int c = 0; c < 3; ++c) {
                short8 fb = *(const short8*)&pin[(rowbase + k) * KA_STR + c * 32 + h * 8];
                acc = __builtin_amdgcn_mfma_f32_16x16x32_bf16(fa[k * 3 + c], fb, acc, 0, 0, 0);
            }
        float v0 = acc[0] + bv.x, v1 = acc[1] + bv.y;
        float v2 = acc[2] + bv.z, v3 = acc[3] + bv.w;
        s1 += (v0 + v1) + (v2 + v3);
        s2 += v0 * v0 + v1 * v1 + v2 * v2 + v3 * v3;
    }
#pragma unroll
    for (int off = 32; off > 0; off >>= 1) {
        s1 += __shfl_xor(s1, off, 64);
        s2 += __shfl_xor(s2, off, 64);
    }
    if (lane == 0) {
        float* pp = part + (((size_t)n * 4 + w) * 32 + lt) * 2;
        pp[0] = s1; pp[1] = s2;
    }
}

__global__ __launch_bounds__(256, 3) void ka_conv(const float* __restrict__ x,
    const float* __restrict__ xe, const float* __restrict__ b1,
    const ushort* __restrict__ w1b, const float* __restrict__ corr,
    float* __restrict__ part, float* __restrict__ out, ushort* __restrict__ xbf)
{
    __shared__ ushort pin[KA_ROWS * KA_STR];   // 27040 B
    const int n = blockIdx.y, chunk = blockIdx.x;
    const int b = n >> 3, g = n & 7, be = n & 15;
    const int t = threadIdx.x;
    const int lane = t & 63, w = t >> 6;       // w = GN group = oc-tile
    const int q = t & 15;

    const float4 corr0 = *(const float4*)&corr[(b << 9) + g * 64 + q * 4];

    KaRegs rg[2];
    ka_load(rg[0], x, xe, b, be, g, chunk * 4 * 128, t);

    // zero pad cols 68..95 once (never overwritten)
#pragma unroll
    for (int i = 0; i < 4; ++i) {
        int pos = t + i * 256;
        if (pos < KA_ROWS * 7) {
            int li = pos / 7, j = pos - li * 7;
            *(uint2*)&pin[li * KA_STR + 68 + j * 4] = make_uint2(0u, 0u);
        }
    }

#pragma unroll
    for (int it = 0; it < 4; ++it) {
        const int lt = chunk * 4 + it;
        const int l0 = lt * 128;
        __syncthreads();                       // pin free from previous MFMA
        ka_write(pin, rg[it & 1], corr0, out, xbf, b, g, n, l0, t);
        if (it < 3)
            ka_load(rg[(it + 1) & 1], x, xe, b, be, g, (lt + 1) * 128, t);
        __syncthreads();                       // pin ready
        ka_mfma(pin, b1, w1b, part, n, lt, w, lane);
    }
}

// ---------------- B: fused second pass (pure compute, linear-copy staging) -
// offs l in [l0, l0+60); h2 j <-> l=l0-1+j; h p <-> l=l0-2+p; rows li <-> l=l0-3+li
#define BT 60
#define XR 66
#define P2S  72
#define H2S  66
template<bool FULL>
__device__ __forceinline__ void kb_body(ushort* smem, float* sstats,
    const float* __restrict__ xe, const ushort* __restrict__ xbf,
    const float* __restrict__ part, const float* __restrict__ b1,
    const ushort* __restrict__ w1b, const float* __restrict__ gn_g,
    const float* __restrict__ gn_b, const float* __restrict__ b2,
    const ushort* __restrict__ w2b, const float* __restrict__ w3,
    float* __restrict__ offs, int n, int lt)
{
    ushort* pin = smem;              // 66*64 = 4224 ush (phases 1-2)
    ushort* xeb = smem + 4224;       // 66*32 = 2112 ush (phases 1-2)
    ushort* p2  = smem;              // 66*72 = 4752 ush (phases 3-4, aliases)
    ushort* h2b = smem + 4752;       // 32*66 = 2112 ush (phases 4-5)
    const int be = n & 15;
    const int l0 = lt * BT;
    const int t = threadIdx.x;
    const int lane = t & 63;
    const int w = t >> 6;            // 0/1

    // stats: wave w reduces GN groups 2w, 2w+1 (part 32 segs/group, L2-hot)
#pragma unroll
    for (int gg = 0; gg < 2; ++gg) {
        int gidx = w * 2 + gg;
        float s1 = 0.f, s2 = 0.f;
        if (lane < 32) {
            float2 p = *(const float2*)&part[(((size_t)n * 4 + gidx) * 32 + lane) * 2];
            s1 = p.x; s2 = p.y;
        }
#pragma unroll
        for (int off = 32; off > 0; off >>= 1) {
            s1 += __shfl_xor(s1, off, 64);
            s2 += __shfl_xor(s2, off, 64);
        }
        if (lane == 0) {
            float mean = s1 * (1.0f / 65536.0f);
            float var  = s2 * (1.0f / 65536.0f) - mean * mean;
            sstats[gidx * 2 + 0] = mean;
            sstats[gidx * 2 + 1] = 1.0f / sqrtf(var + 1e-5f);
        }
    }

    // phase 1a: linear copy xbf -> pin (swizzled chunk placement, no cvt)
    {
        const uint4* xs = (const uint4*)(xbf + ((size_t)n * LL + (l0 - 3)) * 64);
#pragma unroll
        for (int i = 0; i < 5; ++i) {
            int s = t + i * 128;
            if (s < XR * 8) {
                int row = s >> 3, ch = s & 7;
                uint4 v;
                if (FULL) {
                    v = xs[s];
                } else {
                    int l = l0 - 3 + row;
                    v = make_uint4(0u, 0u, 0u, 0u);
                    if (l >= 0 && l < LL) v = xs[s];
                }
                ((uint4*)pin)[(row << 3) | (ch ^ (row & 7))] = v;
            }
        }
    }
    // phase 1b: xe (tiny, L2-hot) -> xeb rows [4 real + 28 zero]
    if (t < XR) {
        int l = l0 - 3 + t;
        float4 v = make_float4(0.f, 0.f, 0.f, 0.f);
        if (FULL || (l >= 0 && l < LL))
            v = *(const float4*)&xe[(size_t)(be * LL + l) * 4];
        uint lo = (uint)f2b(v.x) | ((uint)f2b(v.y) << 16);
        uint hi = (uint)f2b(v.z) | ((uint)f2b(v.w) << 16);
        int sw = t & 3;
        uint4 z = make_uint4(0u, 0u, 0u, 0u);
        ((uint4*)xeb)[(t << 2) | (0 ^ sw)] = make_uint4(lo, hi, 0u, 0u);
        ((uint4*)xeb)[(t << 2) | (1 ^ sw)] = z;
        ((uint4*)xeb)[(t << 2) | (2 ^ sw)] = z;
        ((uint4*)xeb)[(t << 2) | (3 ^ sw)] = z;
    }
    __syncthreads();

    // phase 2: conv1 MFMA (recompute), acc in registers
    const int m = lane & 15, h = lane >> 4;

    short8 fa[2][9];
#pragma unroll
    for (int mi = 0; mi < 2; ++mi)
#pragma unroll
        for (int k = 0; k < 3; ++k)
#pragma unroll
            for (int c = 0; c < 3; ++c)
                fa[mi][k * 3 + c] = *(const short8*)&w1b[
                    (size_t)(k * 64 + w * 32 + mi * 16 + m) * 96 + c * 32 + h * 8];

    f32x4 acc[2][4] = {};
#pragma unroll
    for (int tt = 0; tt < 4; ++tt) {
        const int p = tt * 16 + m;       // h pos; x row = p + k
#pragma unroll
        for (int k = 0; k < 3; ++k) {
            const int row = p + k;
#pragma unroll
            for (int c = 0; c < 3; ++c) {
                short8 fb;
                if (c < 2)
                    fb = *(const short8*)&pin[(size_t)(((row << 3) | ((c * 4 + h) ^ (row & 7))) << 3)];
                else
                    fb = *(const short8*)&xeb[(size_t)(((row << 2) | (h ^ (row & 3))) << 3)];
                acc[0][tt] = __builtin_amdgcn_mfma_f32_16x16x32_bf16(fa[0][k * 3 + c], fb, acc[0][tt], 0, 0, 0);
                acc[1][tt] = __builtin_amdgcn_mfma_f32_16x16x32_bf16(fa[1][k * 3 + c], fb, acc[1][tt], 0, 0, 0);
            }
        }
    }
    __syncthreads();   // pin/xeb dead; p2 may overwrite

    // phase 3: bias+GN+GELU -> p2[p][oc] (bf16), p = 0..63
#pragma unroll
    for (int mi = 0; mi < 2; ++mi) {
        int gi = w * 2 + mi;
        float mean = sstats[gi * 2], istd = sstats[gi * 2 + 1];
        float A_[4], B_[4];
#pragma unroll
        for (int r = 0; r < 4; ++r) {
            int oc = w * 32 + mi * 16 + h * 4 + r;
            float ga = gn_g[oc];
            A_[r] = istd * ga;
            B_[r] = gn_b[oc] + (b1[oc] - mean) * A_[r];
        }
#pragma unroll
        for (int tt = 0; tt < 4; ++tt) {
            int p = tt * 16 + m;
            uint2 pk = make_uint2(0u, 0u);
            int l = l0 - 2 + p;
            if (FULL || (l >= 0 && l < LL)) {
                float v0 = fast_gelu(fmaf(acc[mi][tt][0], A_[0], B_[0]));
                float v1 = fast_gelu(fmaf(acc[mi][tt][1], A_[1], B_[1]));
                float v2 = fast_gelu(fmaf(acc[mi][tt][2], A_[2], B_[2]));
                float v3 = fast_gelu(fmaf(acc[mi][tt][3], A_[3], B_[3]));
                pk.x = (uint)f2b(v0) | ((uint)f2b(v1) << 16);
                pk.y = (uint)f2b(v2) | ((uint)f2b(v3) << 16);
            }
            *(uint2*)&p2[p * P2S + w * 32 + mi * 16 + h * 4] = pk;
        }
    }
    __syncthreads();

    // phase 4: conv2 MFMA + GELU -> h2b; wave w owns oc-tile w (16 oc)
    short8 fa2[6];
#pragma unroll
    for (int k = 0; k < 3; ++k)
#pragma unroll
        for (int c = 0; c < 2; ++c)
            fa2[k * 2 + c] = *(const short8*)&w2b[
                (size_t)(k * 32 + w * 16 + m) * 64 + c * 32 + h * 8];

    float bias2[4];
#pragma unroll
    for (int r = 0; r < 4; ++r)
        bias2[r] = b2[w * 16 + h * 4 + r];

    f32x4 acc2[4] = {};
#pragma unroll
    for (int u = 0; u < 4; ++u) {
        const int jb = u * 16 + m;      // h2 col j; rows>63 only feed unused j
#pragma unroll
        for (int k = 0; k < 3; ++k) {
#pragma unroll
            for (int c = 0; c < 2; ++c) {
                short8 fb = *(const short8*)&p2[(jb + k) * P2S + c * 32 + h * 8];
                acc2[u] = __builtin_amdgcn_mfma_f32_16x16x32_bf16(fa2[k * 2 + c], fb, acc2[u], 0, 0, 0);
            }
        }
    }
#pragma unroll
    for (int u = 0; u < 4; ++u) {
        int j = u * 16 + m;
        int lj = l0 - 1 + j;
#pragma unroll
        for (int r = 0; r < 4; ++r) {
            int oc = w * 16 + h * 4 + r;
            float v = 0.f;
            if (FULL || (lj >= 0 && lj < LL))
                v = fast_gelu(acc2[u][r] + bias2[r]);
            h2b[oc * H2S + j] = f2b(v);    // j=62..65 garbage-adjacent, never read
        }
    }
    __syncthreads();

    // phase 5: conv3 + tanh*10; (qq, half): 16 ic each, pair-reduce
    if (t < 2 * BT) {
        int qq = t >> 1, half = t & 1;
        int ic0 = half * 16;
        float a = 0.f;
#pragma unroll
        for (int ic = 0; ic < 16; ++ic) {
            int icc = ic0 + ic;
            float v0 = b2f(h2b[icc * H2S + qq]);
            float v1 = b2f(h2b[icc * H2S + qq + 1]);
            float v2 = b2f(h2b[icc * H2S + qq + 2]);
            a = fmaf(w3[icc * 3 + 0], v0, a);
            a = fmaf(w3[icc * 3 + 1], v1, a);
            a = fmaf(w3[icc * 3 + 2], v2, a);
        }
        a += __shfl_xor(a, 1, 64);
        if (half == 0) {
            int l = l0 + qq;
            if (FULL || l < LL)
                offs[(size_t)n * LL + l] = fast_tanh(a) * 10.0f;
        }
    }
}

__global__ __launch_bounds__(128, 4) void kb_fused(const float* __restrict__ xe,
    const ushort* __restrict__ xbf, const float* __restrict__ part,
    const float* __restrict__ b1, const ushort* __restrict__ w1b,
    const float* __restrict__ gn_g, const float* __restrict__ gn_b,
    const float* __restrict__ b2, const ushort* __restrict__ w2b,
    const float* __restrict__ w3, float* __restrict__ offs)
{
    __shared__ ushort smem[6864];   // 13728 B: (pin|xeb) aliased by (p2|h2b)
    __shared__ float sstats[8];
    const int n = blockIdx.y, lt = blockIdx.x;
    if (lt >= 1 && lt <= 67)
        kb_body<true >(smem, sstats, xe, xbf, part, b1, w1b, gn_g, gn_b, b2, w2b, w3, offs, n, lt);
    else
        kb_body<false>(smem, sstats, xe, xbf, part, b1, w1b, gn_g, gn_b, b2, w2b, w3, offs, n, lt);
}

extern "C" void kernel_launch(void* const* d_in, const int* in_sizes, int n_in,
                              void* d_out, int out_size, void* d_ws, size_t ws_size,
                              hipStream_t stream)
{
    const float* x    = (const float*)d_in[0];
    const float* xext = (const float*)d_in[1];
    const float* w1   = (const float*)d_in[2];
    const float* b1   = (const float*)d_in[3];
    const float* gng  = (const float*)d_in[4];
    const float* gnb  = (const float*)d_in[5];
    const float* w2   = (const float*)d_in[6];
    const float* b2   = (const float*)d_in[7];
    const float* w3   = (const float*)d_in[8];
    const float* gate = (const float*)d_in[9];

    float* out  = (float*)d_out;
    float* offs = out + (size_t)BB * LL * CC;        // 33,554,432

    char* ws = (char*)d_ws;
    float* part = (float*)(ws);                      // 131,072 B (128*4*32*2 f32)
    ushort* w1b = (ushort*)(ws + 131072);            // 36,864 B
    ushort* w2b = (ushort*)(ws + 167936);            // 12,288 B
    float* corr = (float*)(ws + 180224);             // 32,768 B
    ushort* xbf = (ushort*)(ws + 212992);            // 67,108,864 B

    k_prep<<<128, 256, 0, stream>>>(x, w1, w2, gate, w1b, w2b, corr);
    dim3 g1(8, NG);
    ka_conv<<<g1, 256, 0, stream>>>(x, xext, b1, w1b, corr, part, out, xbf);
    dim3 g3(69, NG);
    kb_fused<<<g3, 128, 0, stream>>>(xext, xbf, part, b1, w1b, gng, gnb, b2, w2b,
                                     w3, offs);
}

// Round 10
// 175.080 us; speedup vs baseline: 1.4481x; 1.2639x over previous
//
#include <hip/hip_runtime.h>
#include <hip/hip_bf16.h>

#define BB 16
#define LL 4096
#define CC 512
#define NG 128   // B*G
#define IC1 68
#define OC1 64
#define OC2 32

typedef short short8 __attribute__((ext_vector_type(8)));
typedef float f32x4 __attribute__((ext_vector_type(4)));

__device__ inline ushort f2b(float f) {
    __hip_bfloat16 h = __float2bfloat16(f);
    return *reinterpret_cast<ushort*>(&h);
}
__device__ inline float b2f(ushort u) {
    __hip_bfloat16 h;
    *reinterpret_cast<ushort*>(&h) = u;
    return __bfloat162float(h);
}
__device__ inline float fast_tanh(float y) {
    float e = __expf(2.0f * y);
    return 1.0f - 2.0f / (e + 1.0f);
}
__device__ inline float fast_gelu(float x) {
    float y = x * (0.7978845608f + 0.0356774081f * x * x);
    return 0.5f * x * (1.0f + fast_tanh(y));
}
__device__ inline float4 add4(float4 a, float4 b) {
    return make_float4(a.x + b.x, a.y + b.y, a.z + b.z, a.w + b.w);
}

// ---------------- prep: bf16 weights (padded), corr ----------------
__global__ __launch_bounds__(256) void k_prep(const float* __restrict__ x,
    const float* __restrict__ w1, const float* __restrict__ w2,
    const float* __restrict__ gate,
    ushort* __restrict__ w1b, ushort* __restrict__ w2b, float* __restrict__ corr)
{
    int idx = blockIdx.x * 256 + threadIdx.x;
    if (idx < 18432) {                       // w1b[k][oc][icp<96]
        int k = idx / 6144; int r = idx - k * 6144;
        int oc = r / 96;    int icp = r - oc * 96;
        float v = (icp < IC1) ? w1[(oc * IC1 + icp) * 3 + k] : 0.0f;
        w1b[idx] = f2b(v);
    } else if (idx < 24576) {                // w2b[k][oc][ic<64]
        int j = idx - 18432;
        int k = j / 2048; int r = j - k * 2048;
        int oc = r / 64;  int ic = r - oc * 64;
        w2b[j] = f2b(w2[(oc * OC1 + ic) * 3 + k]);
    } else if (idx < 32768) {                // corr[b*512+ch]
        int i3 = idx - 24576;
        int b = i3 >> 9; int ch = i3 & 511;
        float tg = tanhf(gate[0]);
        corr[i3] = tg * 0.5f *
            (x[((size_t)(b * LL + 2047)) * CC + ch] +
             x[((size_t)(b * LL + 2048)) * CC + ch]);
    }
}

// ---------------- S: pure stream: out = x + corr, xbf = bf16(x) ----------
// grid-stride, no LDS, no barriers; thread handles 8 channels (32 B)
__global__ __launch_bounds__(256) void ks_stream(const float* __restrict__ x,
    const float* __restrict__ corr, float* __restrict__ out,
    ushort* __restrict__ xbf)
{
    const size_t total8 = (size_t)BB * LL * CC / 8;   // 4,194,304
    size_t i = (size_t)blockIdx.x * 256 + threadIdx.x;
    const size_t stride = (size_t)gridDim.x * 256;
    const float4* x4 = (const float4*)x;
    const float4* c4 = (const float4*)corr;
    float4* o4 = (float4*)out;
    uint4* xb4 = (uint4*)xbf;
    for (; i < total8; i += stride) {
        int c8 = (int)(i & 63);              // 8-ch octet within 512
        size_t bl = i >> 6;
        int l = (int)(bl & (LL - 1));
        int b = (int)(bl >> 12);
        float4 v0 = x4[i * 2];
        float4 v1 = x4[i * 2 + 1];
        float4 c0 = c4[(b << 7) + c8 * 2];
        float4 c1 = c4[(b << 7) + c8 * 2 + 1];
        o4[i * 2]     = add4(v0, c0);
        o4[i * 2 + 1] = add4(v1, c1);
        uint4 pk;
        pk.x = (uint)f2b(v0.x) | ((uint)f2b(v0.y) << 16);
        pk.y = (uint)f2b(v0.z) | ((uint)f2b(v0.w) << 16);
        pk.z = (uint)f2b(v1.x) | ((uint)f2b(v1.y) << 16);
        pk.w = (uint)f2b(v1.z) | ((uint)f2b(v1.w) << 16);
        // xbf[n = b*8 + c8/8][l][ (c8&7)*8 ]
        xb4[((size_t)((b << 3) | (c8 >> 3)) * LL + l) * 8 + (c8 & 7)] = pk;
    }
}

// ---------------- A: conv1 stats from xbf (bf16 linear copy + MFMA) ------
// tile 128 l, 256 threads; wave = GN group; rows li <-> l = l0-1+li
#define KA_ROWS 130
__global__ __launch_bounds__(256) void ka_stats(const ushort* __restrict__ xbf,
    const float* __restrict__ xe, const float* __restrict__ b1,
    const ushort* __restrict__ w1b, float* __restrict__ part)
{
    __shared__ ushort pin[KA_ROWS * 64];   // 16640 B, swizzled 16B chunks
    __shared__ ushort xeb[KA_ROWS * 32];   // 8320 B, swizzled (4 real + 28 zero)
    const int n = blockIdx.y, lt = blockIdx.x;
    const int be = n & 15;
    const int l0 = lt * 128;
    const int t = threadIdx.x;
    const int lane = t & 63, w = t >> 6;   // w = GN group = oc-tile

    // stage xbf -> pin: linear uint4 copy, chunk placed at (ch ^ (row&7))
    {
        const uint4* xs = (const uint4*)(xbf + ((size_t)n * LL + (l0 - 1)) * 64);
#pragma unroll
        for (int i = 0; i < 5; ++i) {
            int s = t + i * 256;
            if (s < KA_ROWS * 8) {
                int row = s >> 3, ch = s & 7;
                int l = l0 - 1 + row;
                uint4 v = make_uint4(0u, 0u, 0u, 0u);
                if ((unsigned)l < (unsigned)LL) v = xs[s];
                ((uint4*)pin)[(row << 3) | (ch ^ (row & 7))] = v;
            }
        }
    }
    // stage xe -> xeb (tiny, L2-hot)
    if (t < KA_ROWS) {
        int l = l0 - 1 + t;
        float4 v = make_float4(0.f, 0.f, 0.f, 0.f);
        if ((unsigned)l < (unsigned)LL)
            v = *(const float4*)&xe[(size_t)(be * LL + l) * 4];
        uint lo = (uint)f2b(v.x) | ((uint)f2b(v.y) << 16);
        uint hi = (uint)f2b(v.z) | ((uint)f2b(v.w) << 16);
        int sw = t & 3;
        uint4 z = make_uint4(0u, 0u, 0u, 0u);
        ((uint4*)xeb)[(t << 2) | (0 ^ sw)] = make_uint4(lo, hi, 0u, 0u);
        ((uint4*)xeb)[(t << 2) | (1 ^ sw)] = z;
        ((uint4*)xeb)[(t << 2) | (2 ^ sw)] = z;
        ((uint4*)xeb)[(t << 2) | (3 ^ sw)] = z;
    }
    __syncthreads();

    // conv1 MFMA for this wave's 16 oc; accumulate group sums only
    const int m = lane & 15, h = lane >> 4;
    short8 fa[9];
#pragma unroll
    for (int k = 0; k < 3; ++k)
#pragma unroll
        for (int c = 0; c < 3; ++c)
            fa[k * 3 + c] = *(const short8*)&w1b[
                (size_t)(k * 64 + w * 16 + m) * 96 + c * 32 + h * 8];

    float4 bv = *(const float4*)&b1[w * 16 + h * 4];
    float s1 = 0.f, s2 = 0.f;
#pragma unroll
    for (int tt = 0; tt < 8; ++tt) {
        f32x4 acc = {};
        const int rowbase = tt * 16 + m;
#pragma unroll
        for (int k = 0; k < 3; ++k) {
            const int row = rowbase + k;
#pragma unroll
            for (int c = 0; c < 3; ++c) {
                short8 fb;
                if (c < 2)
                    fb = *(const short8*)&pin[(size_t)(((row << 3) | ((c * 4 + h) ^ (row & 7))) << 3)];
                else
                    fb = *(const short8*)&xeb[(size_t)(((row << 2) | (h ^ (row & 3))) << 3)];
                acc = __builtin_amdgcn_mfma_f32_16x16x32_bf16(fa[k * 3 + c], fb, acc, 0, 0, 0);
            }
        }
        float v0 = acc[0] + bv.x, v1 = acc[1] + bv.y;
        float v2 = acc[2] + bv.z, v3 = acc[3] + bv.w;
        s1 += (v0 + v1) + (v2 + v3);
        s2 += v0 * v0 + v1 * v1 + v2 * v2 + v3 * v3;
    }
#pragma unroll
    for (int off = 32; off > 0; off >>= 1) {
        s1 += __shfl_xor(s1, off, 64);
        s2 += __shfl_xor(s2, off, 64);
    }
    if (lane == 0) {
        float* pp = part + (((size_t)n * 4 + w) * 32 + lt) * 2;
        pp[0] = s1; pp[1] = s2;
    }
}

// ---------------- B: fused second pass (pure compute, linear-copy staging) -
// offs l in [l0, l0+60); h2 j <-> l=l0-1+j; h p <-> l=l0-2+p; rows li <-> l=l0-3+li
#define BT 60
#define XR 66
#define P2S  72
#define H2S  66
template<bool FULL>
__device__ __forceinline__ void kb_body(ushort* smem, float* sstats,
    const float* __restrict__ xe, const ushort* __restrict__ xbf,
    const float* __restrict__ part, const float* __restrict__ b1,
    const ushort* __restrict__ w1b, const float* __restrict__ gn_g,
    const float* __restrict__ gn_b, const float* __restrict__ b2,
    const ushort* __restrict__ w2b, const float* __restrict__ w3,
    float* __restrict__ offs, int n, int lt)
{
    ushort* pin = smem;              // 66*64 = 4224 ush (phases 1-2)
    ushort* xeb = smem + 4224;       // 66*32 = 2112 ush (phases 1-2)
    ushort* p2  = smem;              // 66*72 = 4752 ush (phases 3-4, aliases)
    ushort* h2b = smem + 4752;       // 32*66 = 2112 ush (phases 4-5)
    const int be = n & 15;
    const int l0 = lt * BT;
    const int t = threadIdx.x;
    const int lane = t & 63;
    const int w = t >> 6;            // 0/1

    // stats: wave w reduces GN groups 2w, 2w+1 (part 32 segs/group, L2-hot)
#pragma unroll
    for (int gg = 0; gg < 2; ++gg) {
        int gidx = w * 2 + gg;
        float s1 = 0.f, s2 = 0.f;
        if (lane < 32) {
            float2 p = *(const float2*)&part[(((size_t)n * 4 + gidx) * 32 + lane) * 2];
            s1 = p.x; s2 = p.y;
        }
#pragma unroll
        for (int off = 32; off > 0; off >>= 1) {
            s1 += __shfl_xor(s1, off, 64);
            s2 += __shfl_xor(s2, off, 64);
        }
        if (lane == 0) {
            float mean = s1 * (1.0f / 65536.0f);
            float var  = s2 * (1.0f / 65536.0f) - mean * mean;
            sstats[gidx * 2 + 0] = mean;
            sstats[gidx * 2 + 1] = 1.0f / sqrtf(var + 1e-5f);
        }
    }

    // phase 1a: linear copy xbf -> pin (swizzled chunk placement, no cvt)
    {
        const uint4* xs = (const uint4*)(xbf + ((size_t)n * LL + (l0 - 3)) * 64);
#pragma unroll
        for (int i = 0; i < 5; ++i) {
            int s = t + i * 128;
            if (s < XR * 8) {
                int row = s >> 3, ch = s & 7;
                uint4 v;
                if (FULL) {
                    v = xs[s];
                } else {
                    int l = l0 - 3 + row;
                    v = make_uint4(0u, 0u, 0u, 0u);
                    if (l >= 0 && l < LL) v = xs[s];
                }
                ((uint4*)pin)[(row << 3) | (ch ^ (row & 7))] = v;
            }
        }
    }
    // phase 1b: xe (tiny, L2-hot) -> xeb rows [4 real + 28 zero]
    if (t < XR) {
        int l = l0 - 3 + t;
        float4 v = make_float4(0.f, 0.f, 0.f, 0.f);
        if (FULL || (l >= 0 && l < LL))
            v = *(const float4*)&xe[(size_t)(be * LL + l) * 4];
        uint lo = (uint)f2b(v.x) | ((uint)f2b(v.y) << 16);
        uint hi = (uint)f2b(v.z) | ((uint)f2b(v.w) << 16);
        int sw = t & 3;
        uint4 z = make_uint4(0u, 0u, 0u, 0u);
        ((uint4*)xeb)[(t << 2) | (0 ^ sw)] = make_uint4(lo, hi, 0u, 0u);
        ((uint4*)xeb)[(t << 2) | (1 ^ sw)] = z;
        ((uint4*)xeb)[(t << 2) | (2 ^ sw)] = z;
        ((uint4*)xeb)[(t << 2) | (3 ^ sw)] = z;
    }
    __syncthreads();

    // phase 2: conv1 MFMA (recompute), acc in registers
    const int m = lane & 15, h = lane >> 4;

    short8 fa[2][9];
#pragma unroll
    for (int mi = 0; mi < 2; ++mi)
#pragma unroll
        for (int k = 0; k < 3; ++k)
#pragma unroll
            for (int c = 0; c < 3; ++c)
                fa[mi][k * 3 + c] = *(const short8*)&w1b[
                    (size_t)(k * 64 + w * 32 + mi * 16 + m) * 96 + c * 32 + h * 8];

    f32x4 acc[2][4] = {};
#pragma unroll
    for (int tt = 0; tt < 4; ++tt) {
        const int p = tt * 16 + m;       // h pos; x row = p + k
#pragma unroll
        for (int k = 0; k < 3; ++k) {
            const int row = p + k;
#pragma unroll
            for (int c = 0; c < 3; ++c) {
                short8 fb;
                if (c < 2)
                    fb = *(const short8*)&pin[(size_t)(((row << 3) | ((c * 4 + h) ^ (row & 7))) << 3)];
                else
                    fb = *(const short8*)&xeb[(size_t)(((row << 2) | (h ^ (row & 3))) << 3)];
                acc[0][tt] = __builtin_amdgcn_mfma_f32_16x16x32_bf16(fa[0][k * 3 + c], fb, acc[0][tt], 0, 0, 0);
                acc[1][tt] = __builtin_amdgcn_mfma_f32_16x16x32_bf16(fa[1][k * 3 + c], fb, acc[1][tt], 0, 0, 0);
            }
        }
    }
    __syncthreads();   // pin/xeb dead; p2 may overwrite

    // phase 3: bias+GN+GELU -> p2[p][oc] (bf16), p = 0..63
#pragma unroll
    for (int mi = 0; mi < 2; ++mi) {
        int gi = w * 2 + mi;
        float mean = sstats[gi * 2], istd = sstats[gi * 2 + 1];
        float A_[4], B_[4];
#pragma unroll
        for (int r = 0; r < 4; ++r) {
            int oc = w * 32 + mi * 16 + h * 4 + r;
            float ga = gn_g[oc];
            A_[r] = istd * ga;
            B_[r] = gn_b[oc] + (b1[oc] - mean) * A_[r];
        }
#pragma unroll
        for (int tt = 0; tt < 4; ++tt) {
            int p = tt * 16 + m;
            uint2 pk = make_uint2(0u, 0u);
            int l = l0 - 2 + p;
            if (FULL || (l >= 0 && l < LL)) {
                float v0 = fast_gelu(fmaf(acc[mi][tt][0], A_[0], B_[0]));
                float v1 = fast_gelu(fmaf(acc[mi][tt][1], A_[1], B_[1]));
                float v2 = fast_gelu(fmaf(acc[mi][tt][2], A_[2], B_[2]));
                float v3 = fast_gelu(fmaf(acc[mi][tt][3], A_[3], B_[3]));
                pk.x = (uint)f2b(v0) | ((uint)f2b(v1) << 16);
                pk.y = (uint)f2b(v2) | ((uint)f2b(v3) << 16);
            }
            *(uint2*)&p2[p * P2S + w * 32 + mi * 16 + h * 4] = pk;
        }
    }
    __syncthreads();

    // phase 4: conv2 MFMA + GELU -> h2b; wave w owns oc-tile w (16 oc)
    short8 fa2[6];
#pragma unroll
    for (int k = 0; k < 3; ++k)
#pragma unroll
        for (int c = 0; c < 2; ++c)
            fa2[k * 2 + c] = *(const short8*)&w2b[
                (size_t)(k * 32 + w * 16 + m) * 64 + c * 32 + h * 8];

    float bias2[4];
#pragma unroll
    for (int r = 0; r < 4; ++r)
        bias2[r] = b2[w * 16 + h * 4 + r];

    f32x4 acc2[4] = {};
#pragma unroll
    for (int u = 0; u < 4; ++u) {
        const int jb = u * 16 + m;      // h2 col j; rows>63 only feed unused j
#pragma unroll
        for (int k = 0; k < 3; ++k) {
#pragma unroll
            for (int c = 0; c < 2; ++c) {
                short8 fb = *(const short8*)&p2[(jb + k) * P2S + c * 32 + h * 8];
                acc2[u] = __builtin_amdgcn_mfma_f32_16x16x32_bf16(fa2[k * 2 + c], fb, acc2[u], 0, 0, 0);
            }
        }
    }
#pragma unroll
    for (int u = 0; u < 4; ++u) {
        int j = u * 16 + m;
        int lj = l0 - 1 + j;
#pragma unroll
        for (int r = 0; r < 4; ++r) {
            int oc = w * 16 + h * 4 + r;
            float v = 0.f;
            if (FULL || (lj >= 0 && lj < LL))
                v = fast_gelu(acc2[u][r] + bias2[r]);
            h2b[oc * H2S + j] = f2b(v);    // j=62..65 garbage-adjacent, never read
        }
    }
    __syncthreads();

    // phase 5: conv3 + tanh*10; (qq, half): 16 ic each, pair-reduce
    if (t < 2 * BT) {
        int qq = t >> 1, half = t & 1;
        int ic0 = half * 16;
        float a = 0.f;
#pragma unroll
        for (int ic = 0; ic < 16; ++ic) {
            int icc = ic0 + ic;
            float v0 = b2f(h2b[icc * H2S + qq]);
            float v1 = b2f(h2b[icc * H2S + qq + 1]);
            float v2 = b2f(h2b[icc * H2S + qq + 2]);
            a = fmaf(w3[icc * 3 + 0], v0, a);
            a = fmaf(w3[icc * 3 + 1], v1, a);
            a = fmaf(w3[icc * 3 + 2], v2, a);
        }
        a += __shfl_xor(a, 1, 64);
        if (half == 0) {
            int l = l0 + qq;
            if (FULL || l < LL)
                offs[(size_t)n * LL + l] = fast_tanh(a) * 10.0f;
        }
    }
}

__global__ __launch_bounds__(128, 4) void kb_fused(const float* __restrict__ xe,
    const ushort* __restrict__ xbf, const float* __restrict__ part,
    const float* __restrict__ b1, const ushort* __restrict__ w1b,
    const float* __restrict__ gn_g, const float* __restrict__ gn_b,
    const float* __restrict__ b2, const ushort* __restrict__ w2b,
    const float* __restrict__ w3, float* __restrict__ offs)
{
    __shared__ ushort smem[6864];   // 13728 B: (pin|xeb) aliased by (p2|h2b)
    __shared__ float sstats[8];
    const int n = blockIdx.y, lt = blockIdx.x;
    if (lt >= 1 && lt <= 67)
        kb_body<true >(smem, sstats, xe, xbf, part, b1, w1b, gn_g, gn_b, b2, w2b, w3, offs, n, lt);
    else
        kb_body<false>(smem, sstats, xe, xbf, part, b1, w1b, gn_g, gn_b, b2, w2b, w3, offs, n, lt);
}

extern "C" void kernel_launch(void* const* d_in, const int* in_sizes, int n_in,
                              void* d_out, int out_size, void* d_ws, size_t ws_size,
                              hipStream_t stream)
{
    const float* x    = (const float*)d_in[0];
    const float* xext = (const float*)d_in[1];
    const float* w1   = (const float*)d_in[2];
    const float* b1   = (const float*)d_in[3];
    const float* gng  = (const float*)d_in[4];
    const float* gnb  = (const float*)d_in[5];
    const float* w2   = (const float*)d_in[6];
    const float* b2   = (const float*)d_in[7];
    const float* w3   = (const float*)d_in[8];
    const float* gate = (const float*)d_in[9];

    float* out  = (float*)d_out;
    float* offs = out + (size_t)BB * LL * CC;        // 33,554,432

    char* ws = (char*)d_ws;
    float* part = (float*)(ws);                      // 131,072 B (128*4*32*2 f32)
    ushort* w1b = (ushort*)(ws + 131072);            // 36,864 B
    ushort* w2b = (ushort*)(ws + 167936);            // 12,288 B
    float* corr = (float*)(ws + 180224);             // 32,768 B
    ushort* xbf = (ushort*)(ws + 212992);            // 67,108,864 B

    k_prep<<<128, 256, 0, stream>>>(x, w1, w2, gate, w1b, w2b, corr);
    ks_stream<<<2048, 256, 0, stream>>>(x, corr, out, xbf);
    dim3 g1(32, NG);
    ka_stats<<<g1, 256, 0, stream>>>(xbf, xext, b1, w1b, part);
    dim3 g3(69, NG);
    kb_fused<<<g3, 128, 0, stream>>>(xext, xbf, part, b1, w1b, gng, gnb, b2, w2b,
                                     w3, offs);
}

// Round 11
// 167.848 us; speedup vs baseline: 1.5105x; 1.0431x over previous
//
#include <hip/hip_runtime.h>
#include <hip/hip_bf16.h>

#define BB 16
#define LL 4096
#define CC 512
#define NG 128   // B*G
#define IC1 68
#define OC1 64
#define OC2 32

typedef short short8 __attribute__((ext_vector_type(8)));
typedef float f32x4 __attribute__((ext_vector_type(4)));

__device__ inline ushort f2b(float f) {
    __hip_bfloat16 h = __float2bfloat16(f);
    return *reinterpret_cast<ushort*>(&h);
}
__device__ inline float b2f(ushort u) {
    __hip_bfloat16 h;
    *reinterpret_cast<ushort*>(&h) = u;
    return __bfloat162float(h);
}
__device__ inline float fast_tanh(float y) {
    float e = __expf(2.0f * y);
    return 1.0f - 2.0f / (e + 1.0f);
}
__device__ inline float fast_gelu(float x) {
    float y = x * (0.7978845608f + 0.0356774081f * x * x);
    return 0.5f * x * (1.0f + fast_tanh(y));
}
__device__ inline float4 add4(float4 a, float4 b) {
    return make_float4(a.x + b.x, a.y + b.y, a.z + b.z, a.w + b.w);
}

// ---------------- prep: bf16 weights (padded), corr ----------------
__global__ __launch_bounds__(256) void k_prep(const float* __restrict__ x,
    const float* __restrict__ w1, const float* __restrict__ w2,
    const float* __restrict__ gate,
    ushort* __restrict__ w1b, ushort* __restrict__ w2b, float* __restrict__ corr)
{
    int idx = blockIdx.x * 256 + threadIdx.x;
    if (idx < 18432) {                       // w1b[k][oc][icp<96]
        int k = idx / 6144; int r = idx - k * 6144;
        int oc = r / 96;    int icp = r - oc * 96;
        float v = (icp < IC1) ? w1[(oc * IC1 + icp) * 3 + k] : 0.0f;
        w1b[idx] = f2b(v);
    } else if (idx < 24576) {                // w2b[k][oc][ic<64]
        int j = idx - 18432;
        int k = j / 2048; int r = j - k * 2048;
        int oc = r / 64;  int ic = r - oc * 64;
        w2b[j] = f2b(w2[(oc * OC1 + ic) * 3 + k]);
    } else if (idx < 32768) {                // corr[b*512+ch]
        int i3 = idx - 24576;
        int b = i3 >> 9; int ch = i3 & 511;
        float tg = tanhf(gate[0]);
        corr[i3] = tg * 0.5f *
            (x[((size_t)(b * LL + 2047)) * CC + ch] +
             x[((size_t)(b * LL + 2048)) * CC + ch]);
    }
}

// ---------------- S: pure stream: out = x + corr, xbf = bf16(x) ----------
// one float4 per thread per iteration -> every instruction fully coalesced
__global__ __launch_bounds__(256) void ks_stream(const float* __restrict__ x,
    const float* __restrict__ corr, float* __restrict__ out,
    ushort* __restrict__ xbf)
{
    const size_t total4 = (size_t)BB * LL * CC / 4;   // 8,388,608
    size_t i = (size_t)blockIdx.x * 256 + threadIdx.x;
    const size_t stride = (size_t)gridDim.x * 256;
    const float4* x4 = (const float4*)x;
    const float4* c4 = (const float4*)corr;
    float4* o4 = (float4*)out;
    uint2* xb2 = (uint2*)xbf;
    for (; i < total4; i += stride) {
        int qc = (int)(i & 127);             // 4-ch quad within 512
        size_t bl = i >> 7;
        int l = (int)(bl & (LL - 1));
        int b = (int)(bl >> 12);
        float4 v = x4[i];
        float4 c = c4[((size_t)b << 7) + qc];
        o4[i] = add4(v, c);
        uint2 pk;
        pk.x = (uint)f2b(v.x) | ((uint)f2b(v.y) << 16);
        pk.y = (uint)f2b(v.z) | ((uint)f2b(v.w) << 16);
        // xbf[n = b*8 + qc/16][l][(qc&15)*4 ch] ; row = 16 uint2
        xb2[((size_t)((b << 3) | (qc >> 4)) * LL + l) * 16 + (qc & 15)] = pk;
    }
}

// ---------------- A: conv1 stats from xbf (bf16 linear copy + MFMA) ------
// tile 128 l, 256 threads; wave = GN group; rows li <-> l = l0-1+li
#define KA_ROWS 130
__global__ __launch_bounds__(256) void ka_stats(const ushort* __restrict__ xbf,
    const float* __restrict__ xe, const float* __restrict__ b1,
    const ushort* __restrict__ w1b, float* __restrict__ part)
{
    __shared__ ushort pin[KA_ROWS * 64];   // 16640 B, swizzled 16B chunks
    __shared__ ushort xeb[KA_ROWS * 32];   // 8320 B, swizzled (4 real + 28 zero)
    const int n = blockIdx.y, lt = blockIdx.x;
    const int be = n & 15;
    const int l0 = lt * 128;
    const int t = threadIdx.x;
    const int lane = t & 63, w = t >> 6;   // w = GN group = oc-tile

    // stage xbf -> pin: linear uint4 copy, chunk placed at (ch ^ (row&7))
    {
        const uint4* xs = (const uint4*)(xbf + ((size_t)n * LL + (l0 - 1)) * 64);
#pragma unroll
        for (int i = 0; i < 5; ++i) {
            int s = t + i * 256;
            if (s < KA_ROWS * 8) {
                int row = s >> 3, ch = s & 7;
                int l = l0 - 1 + row;
                uint4 v = make_uint4(0u, 0u, 0u, 0u);
                if ((unsigned)l < (unsigned)LL) v = xs[s];
                ((uint4*)pin)[(row << 3) | (ch ^ (row & 7))] = v;
            }
        }
    }
    // stage xe -> xeb (tiny, L2-hot)
    if (t < KA_ROWS) {
        int l = l0 - 1 + t;
        float4 v = make_float4(0.f, 0.f, 0.f, 0.f);
        if ((unsigned)l < (unsigned)LL)
            v = *(const float4*)&xe[(size_t)(be * LL + l) * 4];
        uint lo = (uint)f2b(v.x) | ((uint)f2b(v.y) << 16);
        uint hi = (uint)f2b(v.z) | ((uint)f2b(v.w) << 16);
        int sw = t & 3;
        uint4 z = make_uint4(0u, 0u, 0u, 0u);
        ((uint4*)xeb)[(t << 2) | (0 ^ sw)] = make_uint4(lo, hi, 0u, 0u);
        ((uint4*)xeb)[(t << 2) | (1 ^ sw)] = z;
        ((uint4*)xeb)[(t << 2) | (2 ^ sw)] = z;
        ((uint4*)xeb)[(t << 2) | (3 ^ sw)] = z;
    }
    __syncthreads();

    // conv1 MFMA for this wave's 16 oc; accumulate group sums only
    const int m = lane & 15, h = lane >> 4;
    short8 fa[9];
#pragma unroll
    for (int k = 0; k < 3; ++k)
#pragma unroll
        for (int c = 0; c < 3; ++c)
            fa[k * 3 + c] = *(const short8*)&w1b[
                (size_t)(k * 64 + w * 16 + m) * 96 + c * 32 + h * 8];

    float4 bv = *(const float4*)&b1[w * 16 + h * 4];
    float s1 = 0.f, s2 = 0.f;
#pragma unroll
    for (int tt = 0; tt < 8; ++tt) {
        f32x4 acc = {};
        const int rowbase = tt * 16 + m;
#pragma unroll
        for (int k = 0; k < 3; ++k) {
            const int row = rowbase + k;
#pragma unroll
            for (int c = 0; c < 3; ++c) {
                short8 fb;
                if (c < 2)
                    fb = *(const short8*)&pin[(size_t)(((row << 3) | ((c * 4 + h) ^ (row & 7))) << 3)];
                else
                    fb = *(const short8*)&xeb[(size_t)(((row << 2) | (h ^ (row & 3))) << 3)];
                acc = __builtin_amdgcn_mfma_f32_16x16x32_bf16(fa[k * 3 + c], fb, acc, 0, 0, 0);
            }
        }
        float v0 = acc[0] + bv.x, v1 = acc[1] + bv.y;
        float v2 = acc[2] + bv.z, v3 = acc[3] + bv.w;
        s1 += (v0 + v1) + (v2 + v3);
        s2 += v0 * v0 + v1 * v1 + v2 * v2 + v3 * v3;
    }
#pragma unroll
    for (int off = 32; off > 0; off >>= 1) {
        s1 += __shfl_xor(s1, off, 64);
        s2 += __shfl_xor(s2, off, 64);
    }
    if (lane == 0) {
        float* pp = part + (((size_t)n * 4 + w) * 32 + lt) * 2;
        pp[0] = s1; pp[1] = s2;
    }
}

// ---------------- B: fused second pass (pure compute, linear-copy staging) -
// offs l in [l0, l0+60); h2 j <-> l=l0-1+j; h p <-> l=l0-2+p; rows li <-> l=l0-3+li
#define BT 60
#define XR 66
#define P2S  72
#define H2S  66
template<bool FULL>
__device__ __forceinline__ void kb_body(ushort* smem, float* sstats,
    const float* __restrict__ xe, const ushort* __restrict__ xbf,
    const float* __restrict__ part, const float* __restrict__ b1,
    const ushort* __restrict__ w1b, const float* __restrict__ gn_g,
    const float* __restrict__ gn_b, const float* __restrict__ b2,
    const ushort* __restrict__ w2b, const float* __restrict__ w3,
    float* __restrict__ offs, int n, int lt)
{
    ushort* pin = smem;              // 66*64 = 4224 ush (phases 1-2)
    ushort* xeb = smem + 4224;       // 66*32 = 2112 ush (phases 1-2)
    ushort* p2  = smem;              // 66*72 = 4752 ush (phases 3-4, aliases)
    ushort* h2b = smem + 4752;       // 32*66 = 2112 ush (phases 4-5)
    const int be = n & 15;
    const int l0 = lt * BT;
    const int t = threadIdx.x;
    const int lane = t & 63;
    const int w = t >> 6;            // 0/1

    // stats: wave w reduces GN groups 2w, 2w+1 (part 32 segs/group, L2-hot)
#pragma unroll
    for (int gg = 0; gg < 2; ++gg) {
        int gidx = w * 2 + gg;
        float s1 = 0.f, s2 = 0.f;
        if (lane < 32) {
            float2 p = *(const float2*)&part[(((size_t)n * 4 + gidx) * 32 + lane) * 2];
            s1 = p.x; s2 = p.y;
        }
#pragma unroll
        for (int off = 32; off > 0; off >>= 1) {
            s1 += __shfl_xor(s1, off, 64);
            s2 += __shfl_xor(s2, off, 64);
        }
        if (lane == 0) {
            float mean = s1 * (1.0f / 65536.0f);
            float var  = s2 * (1.0f / 65536.0f) - mean * mean;
            sstats[gidx * 2 + 0] = mean;
            sstats[gidx * 2 + 1] = 1.0f / sqrtf(var + 1e-5f);
        }
    }

    // phase 1a: linear copy xbf -> pin (swizzled chunk placement, no cvt)
    {
        const uint4* xs = (const uint4*)(xbf + ((size_t)n * LL + (l0 - 3)) * 64);
#pragma unroll
        for (int i = 0; i < 5; ++i) {
            int s = t + i * 128;
            if (s < XR * 8) {
                int row = s >> 3, ch = s & 7;
                uint4 v;
                if (FULL) {
                    v = xs[s];
                } else {
                    int l = l0 - 3 + row;
                    v = make_uint4(0u, 0u, 0u, 0u);
                    if (l >= 0 && l < LL) v = xs[s];
                }
                ((uint4*)pin)[(row << 3) | (ch ^ (row & 7))] = v;
            }
        }
    }
    // phase 1b: xe (tiny, L2-hot) -> xeb rows [4 real + 28 zero]
    if (t < XR) {
        int l = l0 - 3 + t;
        float4 v = make_float4(0.f, 0.f, 0.f, 0.f);
        if (FULL || (l >= 0 && l < LL))
            v = *(const float4*)&xe[(size_t)(be * LL + l) * 4];
        uint lo = (uint)f2b(v.x) | ((uint)f2b(v.y) << 16);
        uint hi = (uint)f2b(v.z) | ((uint)f2b(v.w) << 16);
        int sw = t & 3;
        uint4 z = make_uint4(0u, 0u, 0u, 0u);
        ((uint4*)xeb)[(t << 2) | (0 ^ sw)] = make_uint4(lo, hi, 0u, 0u);
        ((uint4*)xeb)[(t << 2) | (1 ^ sw)] = z;
        ((uint4*)xeb)[(t << 2) | (2 ^ sw)] = z;
        ((uint4*)xeb)[(t << 2) | (3 ^ sw)] = z;
    }
    __syncthreads();

    // phase 2: conv1 MFMA (recompute), acc in registers
    const int m = lane & 15, h = lane >> 4;

    short8 fa[2][9];
#pragma unroll
    for (int mi = 0; mi < 2; ++mi)
#pragma unroll
        for (int k = 0; k < 3; ++k)
#pragma unroll
            for (int c = 0; c < 3; ++c)
                fa[mi][k * 3 + c] = *(const short8*)&w1b[
                    (size_t)(k * 64 + w * 32 + mi * 16 + m) * 96 + c * 32 + h * 8];

    f32x4 acc[2][4] = {};
#pragma unroll
    for (int tt = 0; tt < 4; ++tt) {
        const int p = tt * 16 + m;       // h pos; x row = p + k
#pragma unroll
        for (int k = 0; k < 3; ++k) {
            const int row = p + k;
#pragma unroll
            for (int c = 0; c < 3; ++c) {
                short8 fb;
                if (c < 2)
                    fb = *(const short8*)&pin[(size_t)(((row << 3) | ((c * 4 + h) ^ (row & 7))) << 3)];
                else
                    fb = *(const short8*)&xeb[(size_t)(((row << 2) | (h ^ (row & 3))) << 3)];
                acc[0][tt] = __builtin_amdgcn_mfma_f32_16x16x32_bf16(fa[0][k * 3 + c], fb, acc[0][tt], 0, 0, 0);
                acc[1][tt] = __builtin_amdgcn_mfma_f32_16x16x32_bf16(fa[1][k * 3 + c], fb, acc[1][tt], 0, 0, 0);
            }
        }
    }
    __syncthreads();   // pin/xeb dead; p2 may overwrite

    // phase 3: bias+GN+GELU -> p2[p][oc] (bf16), p = 0..63
#pragma unroll
    for (int mi = 0; mi < 2; ++mi) {
        int gi = w * 2 + mi;
        float mean = sstats[gi * 2], istd = sstats[gi * 2 + 1];
        float A_[4], B_[4];
#pragma unroll
        for (int r = 0; r < 4; ++r) {
            int oc = w * 32 + mi * 16 + h * 4 + r;
            float ga = gn_g[oc];
            A_[r] = istd * ga;
            B_[r] = gn_b[oc] + (b1[oc] - mean) * A_[r];
        }
#pragma unroll
        for (int tt = 0; tt < 4; ++tt) {
            int p = tt * 16 + m;
            uint2 pk = make_uint2(0u, 0u);
            int l = l0 - 2 + p;
            if (FULL || (l >= 0 && l < LL)) {
                float v0 = fast_gelu(fmaf(acc[mi][tt][0], A_[0], B_[0]));
                float v1 = fast_gelu(fmaf(acc[mi][tt][1], A_[1], B_[1]));
                float v2 = fast_gelu(fmaf(acc[mi][tt][2], A_[2], B_[2]));
                float v3 = fast_gelu(fmaf(acc[mi][tt][3], A_[3], B_[3]));
                pk.x = (uint)f2b(v0) | ((uint)f2b(v1) << 16);
                pk.y = (uint)f2b(v2) | ((uint)f2b(v3) << 16);
            }
            *(uint2*)&p2[p * P2S + w * 32 + mi * 16 + h * 4] = pk;
        }
    }
    __syncthreads();

    // phase 4: conv2 MFMA + GELU -> h2b; wave w owns oc-tile w (16 oc)
    short8 fa2[6];
#pragma unroll
    for (int k = 0; k < 3; ++k)
#pragma unroll
        for (int c = 0; c < 2; ++c)
            fa2[k * 2 + c] = *(const short8*)&w2b[
                (size_t)(k * 32 + w * 16 + m) * 64 + c * 32 + h * 8];

    float bias2[4];
#pragma unroll
    for (int r = 0; r < 4; ++r)
        bias2[r] = b2[w * 16 + h * 4 + r];

    f32x4 acc2[4] = {};
#pragma unroll
    for (int u = 0; u < 4; ++u) {
        const int jb = u * 16 + m;      // h2 col j; rows>63 only feed unused j
#pragma unroll
        for (int k = 0; k < 3; ++k) {
#pragma unroll
            for (int c = 0; c < 2; ++c) {
                short8 fb = *(const short8*)&p2[(jb + k) * P2S + c * 32 + h * 8];
                acc2[u] = __builtin_amdgcn_mfma_f32_16x16x32_bf16(fa2[k * 2 + c], fb, acc2[u], 0, 0, 0);
            }
        }
    }
#pragma unroll
    for (int u = 0; u < 4; ++u) {
        int j = u * 16 + m;
        int lj = l0 - 1 + j;
#pragma unroll
        for (int r = 0; r < 4; ++r) {
            int oc = w * 16 + h * 4 + r;
            float v = 0.f;
            if (FULL || (lj >= 0 && lj < LL))
                v = fast_gelu(acc2[u][r] + bias2[r]);
            h2b[oc * H2S + j] = f2b(v);    // j=62..65 garbage-adjacent, never read
        }
    }
    __syncthreads();

    // phase 5: conv3 + tanh*10; (qq, half): 16 ic each, pair-reduce
    if (t < 2 * BT) {
        int qq = t >> 1, half = t & 1;
        int ic0 = half * 16;
        float a = 0.f;
#pragma unroll
        for (int ic = 0; ic < 16; ++ic) {
            int icc = ic0 + ic;
            float v0 = b2f(h2b[icc * H2S + qq]);
            float v1 = b2f(h2b[icc * H2S + qq + 1]);
            float v2 = b2f(h2b[icc * H2S + qq + 2]);
            a = fmaf(w3[icc * 3 + 0], v0, a);
            a = fmaf(w3[icc * 3 + 1], v1, a);
            a = fmaf(w3[icc * 3 + 2], v2, a);
        }
        a += __shfl_xor(a, 1, 64);
        if (half == 0) {
            int l = l0 + qq;
            if (FULL || l < LL)
                offs[(size_t)n * LL + l] = fast_tanh(a) * 10.0f;
        }
    }
}

__global__ __launch_bounds__(128, 4) void kb_fused(const float* __restrict__ xe,
    const ushort* __restrict__ xbf, const float* __restrict__ part,
    const float* __restrict__ b1, const ushort* __restrict__ w1b,
    const float* __restrict__ gn_g, const float* __restrict__ gn_b,
    const float* __restrict__ b2, const ushort* __restrict__ w2b,
    const float* __restrict__ w3, float* __restrict__ offs)
{
    __shared__ ushort smem[6864];   // 13728 B: (pin|xeb) aliased by (p2|h2b)
    __shared__ float sstats[8];
    const int n = blockIdx.y, lt = blockIdx.x;
    if (lt >= 1 && lt <= 67)
        kb_body<true >(smem, sstats, xe, xbf, part, b1, w1b, gn_g, gn_b, b2, w2b, w3, offs, n, lt);
    else
        kb_body<false>(smem, sstats, xe, xbf, part, b1, w1b, gn_g, gn_b, b2, w2b, w3, offs, n, lt);
}

extern "C" void kernel_launch(void* const* d_in, const int* in_sizes, int n_in,
                              void* d_out, int out_size, void* d_ws, size_t ws_size,
                              hipStream_t stream)
{
    const float* x    = (const float*)d_in[0];
    const float* xext = (const float*)d_in[1];
    const float* w1   = (const float*)d_in[2];
    const float* b1   = (const float*)d_in[3];
    const float* gng  = (const float*)d_in[4];
    const float* gnb  = (const float*)d_in[5];
    const float* w2   = (const float*)d_in[6];
    const float* b2   = (const float*)d_in[7];
    const float* w3   = (const float*)d_in[8];
    const float* gate = (const float*)d_in[9];

    float* out  = (float*)d_out;
    float* offs = out + (size_t)BB * LL * CC;        // 33,554,432

    char* ws = (char*)d_ws;
    float* part = (float*)(ws);                      // 131,072 B (128*4*32*2 f32)
    ushort* w1b = (ushort*)(ws + 131072);            // 36,864 B
    ushort* w2b = (ushort*)(ws + 167936);            // 12,288 B
    float* corr = (float*)(ws + 180224);             // 32,768 B
    ushort* xbf = (ushort*)(ws + 212992);            // 67,108,864 B

    k_prep<<<128, 256, 0, stream>>>(x, w1, w2, gate, w1b, w2b, corr);
    ks_stream<<<4096, 256, 0, stream>>>(x, corr, out, xbf);
    dim3 g1(32, NG);
    ka_stats<<<g1, 256, 0, stream>>>(xbf, xext, b1, w1b, part);
    dim3 g3(69, NG);
    kb_fused<<<g3, 128, 0, stream>>>(xext, xbf, part, b1, w1b, gng, gnb, b2, w2b,
                                     w3, offs);
}